// Round 5
// baseline (240.273 us; speedup 1.0000x reference)
//
#include <hip/hip_runtime.h>
#include <hip/hip_bf16.h>

// CoAttention fp32 in/out; bf16 MFMA internals (32x32x16 pipe).
// cvt(fp32->bf16) -> qkv_gemm -> flash attn.
// R1: attn softmax VALU diet (raw v_exp_f32, cvt_pk_bf16, packed f32).
// R2: 256^2 coarse-phase attempt — REGRESSED (1.5-round tail).
// R3: depth-2 prefetch on 2-barrier loop — NEUTRAL (vmcnt null w/o phases).
// R4: phase schedule, BM256xBN128, tri-buffer — CORRECTNESS BUG: stg
//     rotation expression wrong for cur==1 (staged into live buffer).
// R5: fix stg rotation; thicken phases to 2/K-tile (8 MFMA ≈ 64 cyc per
//     barrier-pair, matching m201's cluster mass). Phase p (kc=2p,2p+1):
//     {10 ds_read_b128 || 3-4 glds tile kt+2} -> s_barrier -> lgkmcnt(0)
//     -> setprio(1) 8 MFMA setprio(0) -> s_barrier. vmcnt(6) once/tile,
//     drain 0 only at kt=15. Grid 32x8x3 = 768 = 3 exact CU rounds.

typedef __attribute__((ext_vector_type(8))) short short8;
typedef __attribute__((ext_vector_type(4))) short short4v;
typedef __attribute__((ext_vector_type(4))) float f32x4;
typedef __attribute__((ext_vector_type(2))) float f32x2;
typedef __attribute__((ext_vector_type(16))) float f32x16;
typedef __attribute__((ext_vector_type(2))) unsigned uint2v;
typedef __attribute__((ext_vector_type(4))) int int4v;

#define AS1(p) ((const __attribute__((address_space(1))) void*)(p))
#define AS3(p) ((__attribute__((address_space(3))) void*)(p))

__device__ inline short f2bs(float x) {
    __hip_bfloat16 h = __float2bfloat16(x);
    return *reinterpret_cast<short*>(&h);
}

// ---------------- convert pass: fp32 -> bf16 ----------------
__global__ __launch_bounds__(256) void cvt_bf16(
    const float* __restrict__ s0, const float* __restrict__ s1,
    const float* __restrict__ s2, const float* __restrict__ s3,
    const float* __restrict__ s4,
    short* __restrict__ d0, short* __restrict__ d1,
    short* __restrict__ d2, short* __restrict__ d3, short* __restrict__ d4)
{
    const float* s; short* d; int n4;
    switch (blockIdx.y) {
        case 0: s = s0; d = d0; n4 = 2097152; break;
        case 1: s = s1; d = d1; n4 = 2097152; break;
        case 2: s = s2; d = d2; n4 = 262144;  break;
        case 3: s = s3; d = d3; n4 = 262144;  break;
        default: s = s4; d = d4; n4 = 262144; break;
    }
    for (int i = blockIdx.x * 256 + threadIdx.x; i < n4; i += gridDim.x * 256) {
        float4 v = ((const float4*)s)[i];
        short4v o;
        o.x = f2bs(v.x); o.y = f2bs(v.y); o.z = f2bs(v.z); o.w = f2bs(v.w);
        ((short4v*)d)[i] = o;
    }
}

// ---------------- QKV GEMM (bf16, NT): C = A @ W^T + b ----------------
// BM=256, BN=128, BK=64, 512 thr = 8 waves. wave (wr=wid>>2, wc=wid&3):
// rows wr*128 + mt*32 (mt 0..3), cols wc*32. Tri-buffer LDS 144 KiB.
__global__ __launch_bounds__(512, 1) void qkv_gemm(
    const short* __restrict__ hsb, const short* __restrict__ kvb,
    const short* __restrict__ wqb, const short* __restrict__ wkb,
    const short* __restrict__ wvb,
    const float* __restrict__ bq, const float* __restrict__ bk,
    const float* __restrict__ bv,
    short* __restrict__ qo, short* __restrict__ ko, short* __restrict__ vo)
{
    const short* A; const short* W; const float* bias; short* dst;
    int z = blockIdx.z;
    if (z == 0)      { A = hsb; W = wqb; bias = bq; dst = qo; }
    else if (z == 1) { A = kvb; W = wkb; bias = bk; dst = ko; }
    else             { A = kvb; W = wvb; bias = bv; dst = vo; }

    __shared__ __align__(16) short As[3][256 * 64];   // 3 x 32 KiB
    __shared__ __align__(16) short Bs[3][128 * 64];   // 3 x 16 KiB

    const int t = threadIdx.x;          // 0..511
    const int lane = t & 63;
    const int wid = t >> 6;             // 0..7
    const int lane31 = lane & 31;
    const int hi = lane >> 5;
    const int wr = wid >> 2;            // 0..1 (128-row half)
    const int wc = wid & 3;             // 0..3 (32-col strip)
    const int m0 = blockIdx.x * 256;
    const int n0 = blockIdx.y * 128;

    f32x16 acc[4] = {};

    // stage helpers: A-tile 256x64 (4 glds/thread), B-tile 128x64 (2 glds/thread)
    auto STAGE_A2 = [&](int buf, int k0, int i0) {   // 2 of the 4 A loads
        #pragma unroll
        for (int i = i0; i < i0 + 2; ++i) {
            int c = i * 512 + t;
            int row = c >> 3;
            int gc = (c & 7) ^ (row & 7);
            __builtin_amdgcn_global_load_lds(
                AS1(&A[(size_t)(m0 + row) * 1024 + k0 + gc * 8]),
                AS3(&As[buf][c * 8]), 16, 0, 0);
        }
    };
    auto STAGE_B2 = [&](int buf, int k0) {           // both B loads
        #pragma unroll
        for (int i = 0; i < 2; ++i) {
            int c = i * 512 + t;
            int row = c >> 3;
            int gc = (c & 7) ^ (row & 7);
            __builtin_amdgcn_global_load_lds(
                AS1(&W[(size_t)(n0 + row) * 1024 + k0 + gc * 8]),
                AS3(&Bs[buf][c * 8]), 16, 0, 0);
        }
    };

    // prologue: tiles 0 and 1 fully staged (12 loads in flight)
    STAGE_A2(0, 0, 0);  STAGE_A2(0, 0, 2);  STAGE_B2(0, 0);
    STAGE_A2(1, 64, 0); STAGE_A2(1, 64, 2); STAGE_B2(1, 64);

    int cur = 0;
    for (int kt = 0; kt < 16; ++kt) {
        // wait for tile kt's 6 loads; tile kt+1's 6 stay in flight
        if (kt == 15) asm volatile("s_waitcnt vmcnt(0)" ::: "memory");
        else          asm volatile("s_waitcnt vmcnt(6)" ::: "memory");
        __builtin_amdgcn_s_barrier();

        const short* as_ = &As[cur][0];
        const short* bs_ = &Bs[cur][0];
        int stg = cur + 2; if (stg >= 3) stg -= 3;   // (cur+2)%3 — R4 bug fixed
        const int k2 = (kt + 2) * 64;
        const bool do_stage = (kt < 14);

        #pragma unroll
        for (int p = 0; p < 2; ++p) {
            // phase p covers kc = 2p, 2p+1: 8 A-frags + 2 B-frags ds_read,
            // plus 3-4 glds of tile kt+2 issued before the barrier.
            short8 af[2][4], bf[2];
            #pragma unroll
            for (int qq = 0; qq < 2; ++qq) {
                const int kc = p * 2 + qq;
                #pragma unroll
                for (int mt = 0; mt < 4; ++mt) {
                    int rr = wr * 128 + mt * 32 + lane31;
                    af[qq][mt] = *(const short8*)&as_[rr * 64 + ((kc * 2 + hi) ^ (rr & 7)) * 8];
                }
                int rn = wc * 32 + lane31;
                bf[qq] = *(const short8*)&bs_[rn * 64 + ((kc * 2 + hi) ^ (rn & 7)) * 8];
            }
            if (do_stage) {
                if (p == 0) { STAGE_A2(stg, k2, 0); STAGE_B2(stg, k2); }
                else        { STAGE_A2(stg, k2, 2); }
            }
            __builtin_amdgcn_s_barrier();
            asm volatile("s_waitcnt lgkmcnt(0)" ::: "memory");
            __builtin_amdgcn_sched_barrier(0);
            __builtin_amdgcn_s_setprio(1);
            #pragma unroll
            for (int qq = 0; qq < 2; ++qq)
                #pragma unroll
                for (int mt = 0; mt < 4; ++mt)
                    acc[mt] = __builtin_amdgcn_mfma_f32_32x32x16_bf16(
                        af[qq][mt], bf[qq], acc[mt], 0, 0, 0);
            __builtin_amdgcn_s_setprio(0);
            __builtin_amdgcn_s_barrier();
        }

        cur = (cur == 2) ? 0 : cur + 1;
    }

    // epilogue: per-wave strip cols n0 + wc*32 + lane31, rows wr*128 + mt*32
    const int col = n0 + wc * 32 + lane31;
    const float bb = bias[col];
    const int h = col >> 6, d = col & 63;
    if (z != 2) {
        #pragma unroll
        for (int mt = 0; mt < 4; ++mt) {
            #pragma unroll
            for (int rg = 0; rg < 4; ++rg) {
                int m = m0 + wr * 128 + mt * 32 + rg * 8 + hi * 4;
                int b = m >> 10, s = m & 1023;
                size_t base = (size_t)((b * 16 + h) * 1024 + s) * 64 + d;
                #pragma unroll
                for (int r = 0; r < 4; ++r)
                    dst[base + (size_t)r * 64] = f2bs(acc[mt][rg * 4 + r] + bb);
            }
        }
    } else {
        // V TRANSPOSED: dst[b][h][d][s]
        #pragma unroll
        for (int mt = 0; mt < 4; ++mt) {
            #pragma unroll
            for (int rg = 0; rg < 4; ++rg) {
                int m = m0 + wr * 128 + mt * 32 + rg * 8 + hi * 4;
                int b = m >> 10, s = m & 1023;
                short4v pk;
                pk.x = f2bs(acc[mt][rg * 4 + 0] + bb);
                pk.y = f2bs(acc[mt][rg * 4 + 1] + bb);
                pk.z = f2bs(acc[mt][rg * 4 + 2] + bb);
                pk.w = f2bs(acc[mt][rg * 4 + 3] + bb);
                *(short4v*)&dst[(size_t)((b * 16 + h) * 64 + d) * 1024 + s] = pk;
            }
        }
    }
}

// ---------------- flash attention ----------------
// 1D grid 1024, XCD swizzle (id&7 = bh low bits). 128 q/block, kv tiles 64 dbuf.
// S^T = K·Q^T (32x32x16) -> no-max softmax (fp32 mask LDS) -> P relayout via
// permlane32_swap (register-only, no Ps LDS) -> O = P·Vt (32x32x16).
#define EXPC 0.18033688011112042f   // 0.125 * log2(e)
#define LOG2E 1.4426950408889634f

__device__ inline uint2v half_swap(unsigned c, unsigned d, int hi) {
#if __has_builtin(__builtin_amdgcn_permlane32_swap)
    return __builtin_amdgcn_permlane32_swap(c, d, false, false);
#else
    unsigned send = hi ? c : d;
    unsigned recv = (unsigned)__shfl_xor((int)send, 32, 64);
    uint2v r;
    r.x = hi ? recv : c;     // frag low dword
    r.y = hi ? d : recv;     // frag high dword
    return r;
#endif
}

// raw v_exp_f32: skips ocml's denorm/overflow guard sequence. Underflow
// flushes to 0 == desired softmax behavior for very-negative/masked scores.
__device__ inline float fast_exp2(float x) {
#if __has_builtin(__builtin_amdgcn_exp2f)
    return __builtin_amdgcn_exp2f(x);
#else
    float r;
    asm("v_exp_f32 %0, %1" : "=v"(r) : "v"(x));
    return r;
#endif
}

// round-to-nearest-even pack of 2 f32 -> 2 bf16 in one dword (lo=a, hi=b)
__device__ inline unsigned cvt_pk_bf16(float a, float b) {
    unsigned r;
    asm("v_cvt_pk_bf16_f32 %0, %1, %2" : "=v"(r) : "v"(a), "v"(b));
    return r;
}

__global__ __launch_bounds__(256, 4) void attn(
    const short* __restrict__ q, const short* __restrict__ k,
    const short* __restrict__ vt, const float* __restrict__ mask,
    float* __restrict__ out)
{
    __shared__ __align__(16) short Ks[2][64 * 64];
    __shared__ __align__(16) short Vs[2][64 * 64];
    __shared__ __align__(16) float Ems[1024];      // fp32 mask * log2(e)

    const int t = threadIdx.x;
    const int lane = t & 63;
    const int wq = t >> 6;
    const int lane31 = lane & 31;
    const int hi = lane >> 5;

    const int id = blockIdx.x;
    const int bh = (id >> 6) * 8 + (id & 7);
    const int qt = (id >> 3) & 7;
    const int b = bh >> 4, h = bh & 15;

    const short* qbase = q + (size_t)(bh * 1024 + qt * 128) * 64;
    const short* kbase = k + (size_t)bh * 1024 * 64;
    const short* vbase = vt + (size_t)bh * 64 * 1024;

    // stage mask once (pre-scaled by log2 e), fp32
    {
        float4 mv = ((const float4*)(mask + b * 1024))[t];
        float4 o4;
        o4.x = mv.x * LOG2E; o4.y = mv.y * LOG2E;
        o4.z = mv.z * LOG2E; o4.w = mv.w * LOG2E;
        *(float4*)&Ems[t * 4] = o4;
    }

    // Q fragments (B-operand: n=q=lane31, k=d), kept in registers
    short8 qf[4];
    #pragma unroll
    for (int kc = 0; kc < 4; ++kc)
        qf[kc] = *(const short8*)&qbase[(size_t)(wq * 32 + lane31) * 64 + kc * 16 + hi * 8];

    // prefetch KV tile 0
    #pragma unroll
    for (int i = 0; i < 2; ++i) {
        int c = i * 256 + t;
        int row = c >> 3;
        int gc = (c & 7) ^ (row & 7);
        __builtin_amdgcn_global_load_lds(AS1(kbase + (size_t)row * 64 + gc * 8),
                                         AS3(&Ks[0][c * 8]), 16, 0, 0);
        __builtin_amdgcn_global_load_lds(AS1(vbase + (size_t)row * 1024 + gc * 8),
                                         AS3(&Vs[0][c * 8]), 16, 0, 0);
    }

    f32x16 o_acc[2] = {};
    f32x2 lacc = {0.f, 0.f};

    for (int kt = 0; kt < 16; ++kt) {
        __syncthreads();
        if (kt < 15) {
            int kv1 = (kt + 1) * 64;
            int nb = (kt + 1) & 1;
            #pragma unroll
            for (int i = 0; i < 2; ++i) {
                int c = i * 256 + t;
                int row = c >> 3;
                int gc = (c & 7) ^ (row & 7);
                __builtin_amdgcn_global_load_lds(
                    AS1(kbase + (size_t)(kv1 + row) * 64 + gc * 8),
                    AS3(&Ks[nb][c * 8]), 16, 0, 0);
                __builtin_amdgcn_global_load_lds(
                    AS1(vbase + (size_t)row * 1024 + kv1 + gc * 8),
                    AS3(&Vs[nb][c * 8]), 16, 0, 0);
            }
        }
        const short* ks_ = Ks[kt & 1];
        const short* vs_ = Vs[kt & 1];
        const int kv0 = kt * 64;

        // S^T[kv][q]: A = K (m=kv), B = Q (n=q). 8 MFMA.
        f32x16 sacc[2] = {};
        #pragma unroll
        for (int kc = 0; kc < 4; ++kc) {
            #pragma unroll
            for (int mt = 0; mt < 2; ++mt) {
                int rr = mt * 32 + lane31;
                short8 ak = *(short8*)&ks_[rr * 64 + ((kc * 2 + hi) ^ (rr & 7)) * 8];
                sacc[mt] = __builtin_amdgcn_mfma_f32_32x32x16_bf16(ak, qf[kc], sacc[mt], 0, 0, 0);
            }
        }

        // softmax numerators; pack p (bf16 pairs) into dwords pk[mt][rg][0..1].
        // lane holds kv = mt*32 + rg*8 + hi*4 + r, q = wq*32 + lane31.
        // packed-f32 fma for exp inputs, raw v_exp, cvt_pk round+pack.
        unsigned pk[2][4][2];
        #pragma unroll
        for (int mt = 0; mt < 2; ++mt) {
            #pragma unroll
            for (int rg = 0; rg < 4; ++rg) {
                int kvl = mt * 32 + rg * 8 + hi * 4;
                f32x4 mk = *(const f32x4*)&Ems[kv0 + kvl];
                f32x4 sv;
                sv.x = sacc[mt][rg * 4 + 0];
                sv.y = sacc[mt][rg * 4 + 1];
                sv.z = sacc[mt][rg * 4 + 2];
                sv.w = sacc[mt][rg * 4 + 3];
                f32x4 ev = sv * EXPC + mk;      // -> v_pk_fma_f32 x2
                float p0 = fast_exp2(ev.x);
                float p1 = fast_exp2(ev.y);
                float p2 = fast_exp2(ev.z);
                float p3 = fast_exp2(ev.w);
                f32x2 pa; pa.x = p0; pa.y = p2;
                f32x2 pb; pb.x = p1; pb.y = p3;
                lacc += pa + pb;                // -> v_pk_add_f32 x2
                pk[mt][rg][0] = cvt_pk_bf16(p0, p1);
                pk[mt][rg][1] = cvt_pk_bf16(p2, p3);
            }
        }

        // O[q][d] += P·Vt. A-frag (m=q=lane31, k=kv=kc*16+hi*8+j) built in-register:
        // groups glo=(kc&1)*2 (c) / glo+1 (d); permlane32_swap gives
        // {dw_j01, dw_j45} = swap(c0,d0), {dw_j23, dw_j67} = swap(c1,d1).
        #pragma unroll
        for (int kc = 0; kc < 4; ++kc) {
            const int mt = kc >> 1, glo = (kc & 1) * 2;
            uint2v s0 = half_swap(pk[mt][glo][0], pk[mt][glo + 1][0], hi);
            uint2v s1 = half_swap(pk[mt][glo][1], pk[mt][glo + 1][1], hi);
            int4v fr; fr.x = (int)s0.x; fr.y = (int)s1.x; fr.z = (int)s0.y; fr.w = (int)s1.y;
            short8 ap = *(short8*)&fr;
            #pragma unroll
            for (int nt = 0; nt < 2; ++nt) {
                int rv = nt * 32 + lane31;
                short8 bv_ = *(short8*)&vs_[rv * 64 + ((kc * 2 + hi) ^ (rv & 7)) * 8];
                o_acc[nt] = __builtin_amdgcn_mfma_f32_32x32x16_bf16(ap, bv_, o_acc[nt], 0, 0, 0);
            }
        }
    }

    // finalize l (halves hold disjoint kv partials for q = wq*32+lane31)
    float l_sum = lacc.x + lacc.y;
    l_sum += __shfl_xor(l_sum, 32, 64);
    float invl = 1.f / l_sum;

    // epilogue: O C-layout row q&31 = rg*8 + hi*4 + r, col d = nt*32 + lane31
    #pragma unroll
    for (int rg = 0; rg < 4; ++rg) {
        #pragma unroll
        for (int r = 0; r < 4; ++r) {
            int qrow_l = rg * 8 + hi * 4 + r;
            float lv = __shfl(invl, qrow_l, 64);
            int qrow = qt * 128 + wq * 32 + qrow_l;
            size_t base = (size_t)(b * 1024 + qrow) * 1024 + h * 64;
            #pragma unroll
            for (int nt = 0; nt < 2; ++nt)
                out[base + nt * 32 + lane31] = o_acc[nt][rg * 4 + r] * lv;
        }
    }
}

extern "C" void kernel_launch(void* const* d_in, const int* in_sizes, int n_in,
                              void* d_out, int out_size, void* d_ws, size_t ws_size,
                              hipStream_t stream) {
    const float* hs   = (const float*)d_in[0];
    const float* kvs  = (const float*)d_in[1];
    const float* mask = (const float*)d_in[2];
    const float* Wq   = (const float*)d_in[3];
    const float* bq   = (const float*)d_in[4];
    const float* Wk   = (const float*)d_in[5];
    const float* bk   = (const float*)d_in[6];
    const float* Wv   = (const float*)d_in[7];
    const float* bv   = (const float*)d_in[8];
    float* outp = (float*)d_out;

    const size_t big = (size_t)8 * 1024 * 1024;
    const size_t wsz = (size_t)1024 * 1024;
    short* q_ws  = (short*)d_ws;
    short* k_ws  = q_ws  + big;
    short* vt_ws = k_ws  + big;
    short* hsb   = vt_ws + big;
    short* kvb   = hsb   + big;
    short* wqb   = kvb   + big;
    short* wkb   = wqb   + wsz;
    short* wvb   = wkb   + wsz;

    cvt_bf16<<<dim3(1024, 5), 256, 0, stream>>>(hs, kvs, Wq, Wk, Wv,
                                                hsb, kvb, wqb, wkb, wvb);
    qkv_gemm<<<dim3(32, 8, 3), 512, 0, stream>>>(hsb, kvb, wqb, wkb, wvb,
                                                 bq, bk, bv, q_ws, k_ws, vt_ws);
    attn<<<dim3(1024), 256, 0, stream>>>(q_ws, k_ws, vt_ws, mask, outp);
}

// Round 7
// 230.415 us; speedup vs baseline: 1.0428x; 1.0428x over previous
//
#include <hip/hip_runtime.h>
#include <hip/hip_bf16.h>

// CoAttention fp32 in/out; bf16 MFMA internals (32x32x16 pipe).
// cvt(fp32->bf16) -> q_gemm + kv_gemm -> flash attn.
// R1: attn softmax VALU diet (raw v_exp_f32, cvt_pk_bf16, packed f32).
// R2/R4/R5: phase-schedule ports — all lost to the plain 2-barrier 128^2
//     loop (single-block lockstep killed cross-block overlap). Reverted.
// R6: keep R1's proven 128^2 2-barrier structure; FUSE K and V GEMMs
//     (shared A = kvb): stage A once + Wk + Wv tiles, 32 MFMA/K-tile
//     against the same 2 barriers -> 2x MFMA per staging/barrier unit.
//     Q-GEMM stays the exact R1 kernel (512 blocks = 2 exact rounds).
// R7: identical resubmit (R6 bench was an infra failure — container died).

typedef __attribute__((ext_vector_type(8))) short short8;
typedef __attribute__((ext_vector_type(4))) short short4v;
typedef __attribute__((ext_vector_type(4))) float f32x4;
typedef __attribute__((ext_vector_type(2))) float f32x2;
typedef __attribute__((ext_vector_type(16))) float f32x16;
typedef __attribute__((ext_vector_type(2))) unsigned uint2v;
typedef __attribute__((ext_vector_type(4))) int int4v;

#define AS1(p) ((const __attribute__((address_space(1))) void*)(p))
#define AS3(p) ((__attribute__((address_space(3))) void*)(p))

__device__ inline short f2bs(float x) {
    __hip_bfloat16 h = __float2bfloat16(x);
    return *reinterpret_cast<short*>(&h);
}

// ---------------- convert pass: fp32 -> bf16 ----------------
__global__ __launch_bounds__(256) void cvt_bf16(
    const float* __restrict__ s0, const float* __restrict__ s1,
    const float* __restrict__ s2, const float* __restrict__ s3,
    const float* __restrict__ s4,
    short* __restrict__ d0, short* __restrict__ d1,
    short* __restrict__ d2, short* __restrict__ d3, short* __restrict__ d4)
{
    const float* s; short* d; int n4;
    switch (blockIdx.y) {
        case 0: s = s0; d = d0; n4 = 2097152; break;
        case 1: s = s1; d = d1; n4 = 2097152; break;
        case 2: s = s2; d = d2; n4 = 262144;  break;
        case 3: s = s3; d = d3; n4 = 262144;  break;
        default: s = s4; d = d4; n4 = 262144; break;
    }
    for (int i = blockIdx.x * 256 + threadIdx.x; i < n4; i += gridDim.x * 256) {
        float4 v = ((const float4*)s)[i];
        short4v o;
        o.x = f2bs(v.x); o.y = f2bs(v.y); o.z = f2bs(v.z); o.w = f2bs(v.w);
        ((short4v*)d)[i] = o;
    }
}

// ---------------- Q GEMM (bf16, NT): C = A @ Wq^T + bq ----------------
// Exact R1 structure: 128x128 tile, BK=64, 256 thr / 4 waves, single-buffer,
// stage -> sync -> compute -> sync. Grid (64,8) = 512 blocks = 2 exact rounds.
__global__ __launch_bounds__(256, 2) void q_gemm(
    const short* __restrict__ hsb, const short* __restrict__ wqb,
    const float* __restrict__ bq, short* __restrict__ qo)
{
    __shared__ __align__(16) short As[128 * 64];
    __shared__ __align__(16) short Bs[128 * 64];

    const int t = threadIdx.x;
    const int lane = t & 63;
    const int wave = t >> 6;
    const int lane31 = lane & 31;
    const int hi = lane >> 5;
    const int wm = (wave & 1) * 64;
    const int wn = (wave >> 1) * 64;
    const int m0 = blockIdx.x * 128;
    const int n0 = blockIdx.y * 128;

    f32x16 acc[2][2] = {};

    for (int k0 = 0; k0 < 1024; k0 += 64) {
        #pragma unroll
        for (int i = 0; i < 4; ++i) {
            int c = i * 256 + t;
            int row = c >> 3;
            int gc = (c & 7) ^ (row & 7);
            __builtin_amdgcn_global_load_lds(
                AS1(&hsb[(size_t)(m0 + row) * 1024 + k0 + gc * 8]), AS3(&As[c * 8]), 16, 0, 0);
            __builtin_amdgcn_global_load_lds(
                AS1(&wqb[(size_t)(n0 + row) * 1024 + k0 + gc * 8]), AS3(&Bs[c * 8]), 16, 0, 0);
        }
        __syncthreads();

        #pragma unroll
        for (int kc = 0; kc < 4; ++kc) {
            short8 af[2], bf[2];
            #pragma unroll
            for (int mt = 0; mt < 2; ++mt) {
                int rr = wm + mt * 32 + lane31;
                af[mt] = *(short8*)&As[rr * 64 + ((kc * 2 + hi) ^ (rr & 7)) * 8];
            }
            #pragma unroll
            for (int nt = 0; nt < 2; ++nt) {
                int rn = wn + nt * 32 + lane31;
                bf[nt] = *(short8*)&Bs[rn * 64 + ((kc * 2 + hi) ^ (rn & 7)) * 8];
            }
            #pragma unroll
            for (int mt = 0; mt < 2; ++mt)
                #pragma unroll
                for (int nt = 0; nt < 2; ++nt)
                    acc[mt][nt] = __builtin_amdgcn_mfma_f32_32x32x16_bf16(
                        af[mt], bf[nt], acc[mt][nt], 0, 0, 0);
        }
        __syncthreads();
    }

    #pragma unroll
    for (int nt = 0; nt < 2; ++nt) {
        int col = n0 + wn + nt * 32 + lane31;
        float bb = bq[col];
        int h = col >> 6, d = col & 63;
        #pragma unroll
        for (int mt = 0; mt < 2; ++mt) {
            #pragma unroll
            for (int rg = 0; rg < 4; ++rg) {
                int m = m0 + wm + mt * 32 + rg * 8 + hi * 4;
                int b = m >> 10, s = m & 1023;
                size_t base = (size_t)((b * 16 + h) * 1024 + s) * 64 + d;
                #pragma unroll
                for (int r = 0; r < 4; ++r)
                    qo[base + (size_t)r * 64] = f2bs(acc[mt][nt][rg * 4 + r] + bb);
            }
        }
    }
}

// ---------------- fused KV GEMM: K = A@Wk^T+bk, V^T = (A@Wv^T+bv)^T ------
// Same 2-barrier structure; A (kvb) staged ONCE, both Wk/Wv tiles staged,
// 32 MFMA per K-tile (2x the MFMA per barrier/staging unit of R1).
__global__ __launch_bounds__(256, 2) void kv_gemm(
    const short* __restrict__ kvb,
    const short* __restrict__ wkb, const short* __restrict__ wvb,
    const float* __restrict__ bk, const float* __restrict__ bv,
    short* __restrict__ ko, short* __restrict__ vo)
{
    __shared__ __align__(16) short As[128 * 64];
    __shared__ __align__(16) short Bk[128 * 64];
    __shared__ __align__(16) short Bv[128 * 64];

    const int t = threadIdx.x;
    const int lane = t & 63;
    const int wave = t >> 6;
    const int lane31 = lane & 31;
    const int hi = lane >> 5;
    const int wm = (wave & 1) * 64;
    const int wn = (wave >> 1) * 64;
    const int m0 = blockIdx.x * 128;
    const int n0 = blockIdx.y * 128;

    f32x16 acck[2][2] = {};
    f32x16 accv[2][2] = {};

    for (int k0 = 0; k0 < 1024; k0 += 64) {
        #pragma unroll
        for (int i = 0; i < 4; ++i) {
            int c = i * 256 + t;
            int row = c >> 3;
            int gc = (c & 7) ^ (row & 7);
            __builtin_amdgcn_global_load_lds(
                AS1(&kvb[(size_t)(m0 + row) * 1024 + k0 + gc * 8]), AS3(&As[c * 8]), 16, 0, 0);
            __builtin_amdgcn_global_load_lds(
                AS1(&wkb[(size_t)(n0 + row) * 1024 + k0 + gc * 8]), AS3(&Bk[c * 8]), 16, 0, 0);
            __builtin_amdgcn_global_load_lds(
                AS1(&wvb[(size_t)(n0 + row) * 1024 + k0 + gc * 8]), AS3(&Bv[c * 8]), 16, 0, 0);
        }
        __syncthreads();

        #pragma unroll
        for (int kc = 0; kc < 4; ++kc) {
            short8 af[2], bfk[2], bfv[2];
            #pragma unroll
            for (int mt = 0; mt < 2; ++mt) {
                int rr = wm + mt * 32 + lane31;
                af[mt] = *(short8*)&As[rr * 64 + ((kc * 2 + hi) ^ (rr & 7)) * 8];
            }
            #pragma unroll
            for (int nt = 0; nt < 2; ++nt) {
                int rn = wn + nt * 32 + lane31;
                int off = rn * 64 + ((kc * 2 + hi) ^ (rn & 7)) * 8;
                bfk[nt] = *(short8*)&Bk[off];
                bfv[nt] = *(short8*)&Bv[off];
            }
            #pragma unroll
            for (int mt = 0; mt < 2; ++mt)
                #pragma unroll
                for (int nt = 0; nt < 2; ++nt) {
                    acck[mt][nt] = __builtin_amdgcn_mfma_f32_32x32x16_bf16(
                        af[mt], bfk[nt], acck[mt][nt], 0, 0, 0);
                    accv[mt][nt] = __builtin_amdgcn_mfma_f32_32x32x16_bf16(
                        af[mt], bfv[nt], accv[mt][nt], 0, 0, 0);
                }
        }
        __syncthreads();
    }

    // K epilogue: standard [b][h][s][d]
    #pragma unroll
    for (int nt = 0; nt < 2; ++nt) {
        int col = n0 + wn + nt * 32 + lane31;
        float bb = bk[col];
        int h = col >> 6, d = col & 63;
        #pragma unroll
        for (int mt = 0; mt < 2; ++mt) {
            #pragma unroll
            for (int rg = 0; rg < 4; ++rg) {
                int m = m0 + wm + mt * 32 + rg * 8 + hi * 4;
                int b = m >> 10, s = m & 1023;
                size_t base = (size_t)((b * 16 + h) * 1024 + s) * 64 + d;
                #pragma unroll
                for (int r = 0; r < 4; ++r)
                    ko[base + (size_t)r * 64] = f2bs(acck[mt][nt][rg * 4 + r] + bb);
            }
        }
    }
    // V epilogue: TRANSPOSED [b][h][d][s]
    #pragma unroll
    for (int nt = 0; nt < 2; ++nt) {
        int col = n0 + wn + nt * 32 + lane31;
        float bb = bv[col];
        int h = col >> 6, d = col & 63;
        #pragma unroll
        for (int mt = 0; mt < 2; ++mt) {
            #pragma unroll
            for (int rg = 0; rg < 4; ++rg) {
                int m = m0 + wm + mt * 32 + rg * 8 + hi * 4;
                int b = m >> 10, s = m & 1023;
                short4v pk;
                pk.x = f2bs(accv[mt][nt][rg * 4 + 0] + bb);
                pk.y = f2bs(accv[mt][nt][rg * 4 + 1] + bb);
                pk.z = f2bs(accv[mt][nt][rg * 4 + 2] + bb);
                pk.w = f2bs(accv[mt][nt][rg * 4 + 3] + bb);
                *(short4v*)&vo[(size_t)((b * 16 + h) * 64 + d) * 1024 + s] = pk;
            }
        }
    }
}

// ---------------- flash attention ----------------
// 1D grid 1024, XCD swizzle (id&7 = bh low bits). 128 q/block, kv tiles 64 dbuf.
// S^T = K·Q^T (32x32x16) -> no-max softmax (fp32 mask LDS) -> P relayout via
// permlane32_swap (register-only, no Ps LDS) -> O = P·Vt (32x32x16).
#define EXPC 0.18033688011112042f   // 0.125 * log2(e)
#define LOG2E 1.4426950408889634f

__device__ inline uint2v half_swap(unsigned c, unsigned d, int hi) {
#if __has_builtin(__builtin_amdgcn_permlane32_swap)
    return __builtin_amdgcn_permlane32_swap(c, d, false, false);
#else
    unsigned send = hi ? c : d;
    unsigned recv = (unsigned)__shfl_xor((int)send, 32, 64);
    uint2v r;
    r.x = hi ? recv : c;     // frag low dword
    r.y = hi ? d : recv;     // frag high dword
    return r;
#endif
}

// raw v_exp_f32: skips ocml's denorm/overflow guard sequence. Underflow
// flushes to 0 == desired softmax behavior for very-negative/masked scores.
__device__ inline float fast_exp2(float x) {
#if __has_builtin(__builtin_amdgcn_exp2f)
    return __builtin_amdgcn_exp2f(x);
#else
    float r;
    asm("v_exp_f32 %0, %1" : "=v"(r) : "v"(x));
    return r;
#endif
}

// round-to-nearest-even pack of 2 f32 -> 2 bf16 in one dword (lo=a, hi=b)
__device__ inline unsigned cvt_pk_bf16(float a, float b) {
    unsigned r;
    asm("v_cvt_pk_bf16_f32 %0, %1, %2" : "=v"(r) : "v"(a), "v"(b));
    return r;
}

__global__ __launch_bounds__(256, 4) void attn(
    const short* __restrict__ q, const short* __restrict__ k,
    const short* __restrict__ vt, const float* __restrict__ mask,
    float* __restrict__ out)
{
    __shared__ __align__(16) short Ks[2][64 * 64];
    __shared__ __align__(16) short Vs[2][64 * 64];
    __shared__ __align__(16) float Ems[1024];      // fp32 mask * log2(e)

    const int t = threadIdx.x;
    const int lane = t & 63;
    const int wq = t >> 6;
    const int lane31 = lane & 31;
    const int hi = lane >> 5;

    const int id = blockIdx.x;
    const int bh = (id >> 6) * 8 + (id & 7);
    const int qt = (id >> 3) & 7;
    const int b = bh >> 4, h = bh & 15;

    const short* qbase = q + (size_t)(bh * 1024 + qt * 128) * 64;
    const short* kbase = k + (size_t)bh * 1024 * 64;
    const short* vbase = vt + (size_t)bh * 64 * 1024;

    // stage mask once (pre-scaled by log2 e), fp32
    {
        float4 mv = ((const float4*)(mask + b * 1024))[t];
        float4 o4;
        o4.x = mv.x * LOG2E; o4.y = mv.y * LOG2E;
        o4.z = mv.z * LOG2E; o4.w = mv.w * LOG2E;
        *(float4*)&Ems[t * 4] = o4;
    }

    // Q fragments (B-operand: n=q=lane31, k=d), kept in registers
    short8 qf[4];
    #pragma unroll
    for (int kc = 0; kc < 4; ++kc)
        qf[kc] = *(const short8*)&qbase[(size_t)(wq * 32 + lane31) * 64 + kc * 16 + hi * 8];

    // prefetch KV tile 0
    #pragma unroll
    for (int i = 0; i < 2; ++i) {
        int c = i * 256 + t;
        int row = c >> 3;
        int gc = (c & 7) ^ (row & 7);
        __builtin_amdgcn_global_load_lds(AS1(kbase + (size_t)row * 64 + gc * 8),
                                         AS3(&Ks[0][c * 8]), 16, 0, 0);
        __builtin_amdgcn_global_load_lds(AS1(vbase + (size_t)row * 1024 + gc * 8),
                                         AS3(&Vs[0][c * 8]), 16, 0, 0);
    }

    f32x16 o_acc[2] = {};
    f32x2 lacc = {0.f, 0.f};

    for (int kt = 0; kt < 16; ++kt) {
        __syncthreads();
        if (kt < 15) {
            int kv1 = (kt + 1) * 64;
            int nb = (kt + 1) & 1;
            #pragma unroll
            for (int i = 0; i < 2; ++i) {
                int c = i * 256 + t;
                int row = c >> 3;
                int gc = (c & 7) ^ (row & 7);
                __builtin_amdgcn_global_load_lds(
                    AS1(kbase + (size_t)(kv1 + row) * 64 + gc * 8),
                    AS3(&Ks[nb][c * 8]), 16, 0, 0);
                __builtin_amdgcn_global_load_lds(
                    AS1(vbase + (size_t)row * 1024 + kv1 + gc * 8),
                    AS3(&Vs[nb][c * 8]), 16, 0, 0);
            }
        }
        const short* ks_ = Ks[kt & 1];
        const short* vs_ = Vs[kt & 1];
        const int kv0 = kt * 64;

        // S^T[kv][q]: A = K (m=kv), B = Q (n=q). 8 MFMA.
        f32x16 sacc[2] = {};
        #pragma unroll
        for (int kc = 0; kc < 4; ++kc) {
            #pragma unroll
            for (int mt = 0; mt < 2; ++mt) {
                int rr = mt * 32 + lane31;
                short8 ak = *(short8*)&ks_[rr * 64 + ((kc * 2 + hi) ^ (rr & 7)) * 8];
                sacc[mt] = __builtin_amdgcn_mfma_f32_32x32x16_bf16(ak, qf[kc], sacc[mt], 0, 0, 0);
            }
        }

        // softmax numerators; pack p (bf16 pairs) into dwords pk[mt][rg][0..1].
        // lane holds kv = mt*32 + rg*8 + hi*4 + r, q = wq*32 + lane31.
        // packed-f32 fma for exp inputs, raw v_exp, cvt_pk round+pack.
        unsigned pk[2][4][2];
        #pragma unroll
        for (int mt = 0; mt < 2; ++mt) {
            #pragma unroll
            for (int rg = 0; rg < 4; ++rg) {
                int kvl = mt * 32 + rg * 8 + hi * 4;
                f32x4 mk = *(const f32x4*)&Ems[kv0 + kvl];
                f32x4 sv;
                sv.x = sacc[mt][rg * 4 + 0];
                sv.y = sacc[mt][rg * 4 + 1];
                sv.z = sacc[mt][rg * 4 + 2];
                sv.w = sacc[mt][rg * 4 + 3];
                f32x4 ev = sv * EXPC + mk;      // -> v_pk_fma_f32 x2
                float p0 = fast_exp2(ev.x);
                float p1 = fast_exp2(ev.y);
                float p2 = fast_exp2(ev.z);
                float p3 = fast_exp2(ev.w);
                f32x2 pa; pa.x = p0; pa.y = p2;
                f32x2 pb; pb.x = p1; pb.y = p3;
                lacc += pa + pb;                // -> v_pk_add_f32 x2
                pk[mt][rg][0] = cvt_pk_bf16(p0, p1);
                pk[mt][rg][1] = cvt_pk_bf16(p2, p3);
            }
        }

        // O[q][d] += P·Vt. A-frag (m=q=lane31, k=kv=kc*16+hi*8+j) built in-register:
        // groups glo=(kc&1)*2 (c) / glo+1 (d); permlane32_swap gives
        // {dw_j01, dw_j45} = swap(c0,d0), {dw_j23, dw_j67} = swap(c1,d1).
        #pragma unroll
        for (int kc = 0; kc < 4; ++kc) {
            const int mt = kc >> 1, glo = (kc & 1) * 2;
            uint2v s0 = half_swap(pk[mt][glo][0], pk[mt][glo + 1][0], hi);
            uint2v s1 = half_swap(pk[mt][glo][1], pk[mt][glo + 1][1], hi);
            int4v fr; fr.x = (int)s0.x; fr.y = (int)s1.x; fr.z = (int)s0.y; fr.w = (int)s1.y;
            short8 ap = *(short8*)&fr;
            #pragma unroll
            for (int nt = 0; nt < 2; ++nt) {
                int rv = nt * 32 + lane31;
                short8 bv_ = *(short8*)&vs_[rv * 64 + ((kc * 2 + hi) ^ (rv & 7)) * 8];
                o_acc[nt] = __builtin_amdgcn_mfma_f32_32x32x16_bf16(ap, bv_, o_acc[nt], 0, 0, 0);
            }
        }
    }

    // finalize l (halves hold disjoint kv partials for q = wq*32+lane31)
    float l_sum = lacc.x + lacc.y;
    l_sum += __shfl_xor(l_sum, 32, 64);
    float invl = 1.f / l_sum;

    // epilogue: O C-layout row q&31 = rg*8 + hi*4 + r, col d = nt*32 + lane31
    #pragma unroll
    for (int rg = 0; rg < 4; ++rg) {
        #pragma unroll
        for (int r = 0; r < 4; ++r) {
            int qrow_l = rg * 8 + hi * 4 + r;
            float lv = __shfl(invl, qrow_l, 64);
            int qrow = qt * 128 + wq * 32 + qrow_l;
            size_t base = (size_t)(b * 1024 + qrow) * 1024 + h * 64;
            #pragma unroll
            for (int nt = 0; nt < 2; ++nt)
                out[base + nt * 32 + lane31] = o_acc[nt][rg * 4 + r] * lv;
        }
    }
}

extern "C" void kernel_launch(void* const* d_in, const int* in_sizes, int n_in,
                              void* d_out, int out_size, void* d_ws, size_t ws_size,
                              hipStream_t stream) {
    const float* hs   = (const float*)d_in[0];
    const float* kvs  = (const float*)d_in[1];
    const float* mask = (const float*)d_in[2];
    const float* Wq   = (const float*)d_in[3];
    const float* bq   = (const float*)d_in[4];
    const float* Wk   = (const float*)d_in[5];
    const float* bk   = (const float*)d_in[6];
    const float* Wv   = (const float*)d_in[7];
    const float* bv   = (const float*)d_in[8];
    float* outp = (float*)d_out;

    const size_t big = (size_t)8 * 1024 * 1024;
    const size_t wsz = (size_t)1024 * 1024;
    short* q_ws  = (short*)d_ws;
    short* k_ws  = q_ws  + big;
    short* vt_ws = k_ws  + big;
    short* hsb   = vt_ws + big;
    short* kvb   = hsb   + big;
    short* wqb   = kvb   + big;
    short* wkb   = wqb   + wsz;
    short* wvb   = wkb   + wsz;

    cvt_bf16<<<dim3(1024, 5), 256, 0, stream>>>(hs, kvs, Wq, Wk, Wv,
                                                hsb, kvb, wqb, wkb, wvb);
    q_gemm<<<dim3(64, 8), 256, 0, stream>>>(hsb, wqb, bq, q_ws);
    kv_gemm<<<dim3(64, 8), 256, 0, stream>>>(kvb, wkb, wvb, bk, bv, k_ws, vt_ws);
    attn<<<dim3(1024), 256, 0, stream>>>(q_ws, k_ws, vt_ws, mask, outp);
}

// Round 8
// 227.716 us; speedup vs baseline: 1.0551x; 1.0119x over previous
//
#include <hip/hip_runtime.h>
#include <hip/hip_bf16.h>

// CoAttention fp32 in/out; bf16 MFMA internals (32x32x16 pipe).
// cvt(fp32->bf16) -> q_gemm + kv_gemm -> flash attn.
// R1: attn softmax VALU diet (raw v_exp_f32, cvt_pk_bf16, packed f32).
// R2/R4/R5: phase-schedule ports — all regressed/neutral. Reverted.
// R6/R7: fused KV GEMM (shared A staged once, 32 MFMA/K-tile) — WIN,
//     q_gemm+kv_gemm both below attn now.
// R8: attn q=64 rows/wave (QBLK=256, 512 blocks = 2 exact rounds):
//     each K/V ds_read_b128 now feeds 2 MFMAs (0.5 reads/MFMA) -> LDS
//     traffic, bank conflicts, mask reads, K/V staging all halve per unit
//     work. VGPR ~200 -> 2 waves/SIMD (launch_bounds 256,2).

typedef __attribute__((ext_vector_type(8))) short short8;
typedef __attribute__((ext_vector_type(4))) short short4v;
typedef __attribute__((ext_vector_type(4))) float f32x4;
typedef __attribute__((ext_vector_type(2))) float f32x2;
typedef __attribute__((ext_vector_type(16))) float f32x16;
typedef __attribute__((ext_vector_type(2))) unsigned uint2v;
typedef __attribute__((ext_vector_type(4))) int int4v;

#define AS1(p) ((const __attribute__((address_space(1))) void*)(p))
#define AS3(p) ((__attribute__((address_space(3))) void*)(p))

__device__ inline short f2bs(float x) {
    __hip_bfloat16 h = __float2bfloat16(x);
    return *reinterpret_cast<short*>(&h);
}

// ---------------- convert pass: fp32 -> bf16 ----------------
__global__ __launch_bounds__(256) void cvt_bf16(
    const float* __restrict__ s0, const float* __restrict__ s1,
    const float* __restrict__ s2, const float* __restrict__ s3,
    const float* __restrict__ s4,
    short* __restrict__ d0, short* __restrict__ d1,
    short* __restrict__ d2, short* __restrict__ d3, short* __restrict__ d4)
{
    const float* s; short* d; int n4;
    switch (blockIdx.y) {
        case 0: s = s0; d = d0; n4 = 2097152; break;
        case 1: s = s1; d = d1; n4 = 2097152; break;
        case 2: s = s2; d = d2; n4 = 262144;  break;
        case 3: s = s3; d = d3; n4 = 262144;  break;
        default: s = s4; d = d4; n4 = 262144; break;
    }
    for (int i = blockIdx.x * 256 + threadIdx.x; i < n4; i += gridDim.x * 256) {
        float4 v = ((const float4*)s)[i];
        short4v o;
        o.x = f2bs(v.x); o.y = f2bs(v.y); o.z = f2bs(v.z); o.w = f2bs(v.w);
        ((short4v*)d)[i] = o;
    }
}

// ---------------- Q GEMM (bf16, NT): C = A @ Wq^T + bq ----------------
__global__ __launch_bounds__(256, 2) void q_gemm(
    const short* __restrict__ hsb, const short* __restrict__ wqb,
    const float* __restrict__ bq, short* __restrict__ qo)
{
    __shared__ __align__(16) short As[128 * 64];
    __shared__ __align__(16) short Bs[128 * 64];

    const int t = threadIdx.x;
    const int lane = t & 63;
    const int wave = t >> 6;
    const int lane31 = lane & 31;
    const int hi = lane >> 5;
    const int wm = (wave & 1) * 64;
    const int wn = (wave >> 1) * 64;
    const int m0 = blockIdx.x * 128;
    const int n0 = blockIdx.y * 128;

    f32x16 acc[2][2] = {};

    for (int k0 = 0; k0 < 1024; k0 += 64) {
        #pragma unroll
        for (int i = 0; i < 4; ++i) {
            int c = i * 256 + t;
            int row = c >> 3;
            int gc = (c & 7) ^ (row & 7);
            __builtin_amdgcn_global_load_lds(
                AS1(&hsb[(size_t)(m0 + row) * 1024 + k0 + gc * 8]), AS3(&As[c * 8]), 16, 0, 0);
            __builtin_amdgcn_global_load_lds(
                AS1(&wqb[(size_t)(n0 + row) * 1024 + k0 + gc * 8]), AS3(&Bs[c * 8]), 16, 0, 0);
        }
        __syncthreads();

        #pragma unroll
        for (int kc = 0; kc < 4; ++kc) {
            short8 af[2], bf[2];
            #pragma unroll
            for (int mt = 0; mt < 2; ++mt) {
                int rr = wm + mt * 32 + lane31;
                af[mt] = *(short8*)&As[rr * 64 + ((kc * 2 + hi) ^ (rr & 7)) * 8];
            }
            #pragma unroll
            for (int nt = 0; nt < 2; ++nt) {
                int rn = wn + nt * 32 + lane31;
                bf[nt] = *(short8*)&Bs[rn * 64 + ((kc * 2 + hi) ^ (rn & 7)) * 8];
            }
            #pragma unroll
            for (int mt = 0; mt < 2; ++mt)
                #pragma unroll
                for (int nt = 0; nt < 2; ++nt)
                    acc[mt][nt] = __builtin_amdgcn_mfma_f32_32x32x16_bf16(
                        af[mt], bf[nt], acc[mt][nt], 0, 0, 0);
        }
        __syncthreads();
    }

    #pragma unroll
    for (int nt = 0; nt < 2; ++nt) {
        int col = n0 + wn + nt * 32 + lane31;
        float bb = bq[col];
        int h = col >> 6, d = col & 63;
        #pragma unroll
        for (int mt = 0; mt < 2; ++mt) {
            #pragma unroll
            for (int rg = 0; rg < 4; ++rg) {
                int m = m0 + wm + mt * 32 + rg * 8 + hi * 4;
                int b = m >> 10, s = m & 1023;
                size_t base = (size_t)((b * 16 + h) * 1024 + s) * 64 + d;
                #pragma unroll
                for (int r = 0; r < 4; ++r)
                    qo[base + (size_t)r * 64] = f2bs(acc[mt][nt][rg * 4 + r] + bb);
            }
        }
    }
}

// ---------------- fused KV GEMM: K = A@Wk^T+bk, V^T = (A@Wv^T+bv)^T ------
__global__ __launch_bounds__(256, 2) void kv_gemm(
    const short* __restrict__ kvb,
    const short* __restrict__ wkb, const short* __restrict__ wvb,
    const float* __restrict__ bk, const float* __restrict__ bv,
    short* __restrict__ ko, short* __restrict__ vo)
{
    __shared__ __align__(16) short As[128 * 64];
    __shared__ __align__(16) short Bk[128 * 64];
    __shared__ __align__(16) short Bv[128 * 64];

    const int t = threadIdx.x;
    const int lane = t & 63;
    const int wave = t >> 6;
    const int lane31 = lane & 31;
    const int hi = lane >> 5;
    const int wm = (wave & 1) * 64;
    const int wn = (wave >> 1) * 64;
    const int m0 = blockIdx.x * 128;
    const int n0 = blockIdx.y * 128;

    f32x16 acck[2][2] = {};
    f32x16 accv[2][2] = {};

    for (int k0 = 0; k0 < 1024; k0 += 64) {
        #pragma unroll
        for (int i = 0; i < 4; ++i) {
            int c = i * 256 + t;
            int row = c >> 3;
            int gc = (c & 7) ^ (row & 7);
            __builtin_amdgcn_global_load_lds(
                AS1(&kvb[(size_t)(m0 + row) * 1024 + k0 + gc * 8]), AS3(&As[c * 8]), 16, 0, 0);
            __builtin_amdgcn_global_load_lds(
                AS1(&wkb[(size_t)(n0 + row) * 1024 + k0 + gc * 8]), AS3(&Bk[c * 8]), 16, 0, 0);
            __builtin_amdgcn_global_load_lds(
                AS1(&wvb[(size_t)(n0 + row) * 1024 + k0 + gc * 8]), AS3(&Bv[c * 8]), 16, 0, 0);
        }
        __syncthreads();

        #pragma unroll
        for (int kc = 0; kc < 4; ++kc) {
            short8 af[2], bfk[2], bfv[2];
            #pragma unroll
            for (int mt = 0; mt < 2; ++mt) {
                int rr = wm + mt * 32 + lane31;
                af[mt] = *(short8*)&As[rr * 64 + ((kc * 2 + hi) ^ (rr & 7)) * 8];
            }
            #pragma unroll
            for (int nt = 0; nt < 2; ++nt) {
                int rn = wn + nt * 32 + lane31;
                int off = rn * 64 + ((kc * 2 + hi) ^ (rn & 7)) * 8;
                bfk[nt] = *(short8*)&Bk[off];
                bfv[nt] = *(short8*)&Bv[off];
            }
            #pragma unroll
            for (int mt = 0; mt < 2; ++mt)
                #pragma unroll
                for (int nt = 0; nt < 2; ++nt) {
                    acck[mt][nt] = __builtin_amdgcn_mfma_f32_32x32x16_bf16(
                        af[mt], bfk[nt], acck[mt][nt], 0, 0, 0);
                    accv[mt][nt] = __builtin_amdgcn_mfma_f32_32x32x16_bf16(
                        af[mt], bfv[nt], accv[mt][nt], 0, 0, 0);
                }
        }
        __syncthreads();
    }

    // K epilogue: standard [b][h][s][d]
    #pragma unroll
    for (int nt = 0; nt < 2; ++nt) {
        int col = n0 + wn + nt * 32 + lane31;
        float bb = bk[col];
        int h = col >> 6, d = col & 63;
        #pragma unroll
        for (int mt = 0; mt < 2; ++mt) {
            #pragma unroll
            for (int rg = 0; rg < 4; ++rg) {
                int m = m0 + wm + mt * 32 + rg * 8 + hi * 4;
                int b = m >> 10, s = m & 1023;
                size_t base = (size_t)((b * 16 + h) * 1024 + s) * 64 + d;
                #pragma unroll
                for (int r = 0; r < 4; ++r)
                    ko[base + (size_t)r * 64] = f2bs(acck[mt][nt][rg * 4 + r] + bb);
            }
        }
    }
    // V epilogue: TRANSPOSED [b][h][d][s]
    #pragma unroll
    for (int nt = 0; nt < 2; ++nt) {
        int col = n0 + wn + nt * 32 + lane31;
        float bb = bv[col];
        int h = col >> 6, d = col & 63;
        #pragma unroll
        for (int mt = 0; mt < 2; ++mt) {
            #pragma unroll
            for (int rg = 0; rg < 4; ++rg) {
                int m = m0 + wm + mt * 32 + rg * 8 + hi * 4;
                int b = m >> 10, s = m & 1023;
                short4v pk;
                pk.x = f2bs(accv[mt][nt][rg * 4 + 0] + bb);
                pk.y = f2bs(accv[mt][nt][rg * 4 + 1] + bb);
                pk.z = f2bs(accv[mt][nt][rg * 4 + 2] + bb);
                pk.w = f2bs(accv[mt][nt][rg * 4 + 3] + bb);
                *(short4v*)&vo[(size_t)((b * 16 + h) * 64 + d) * 1024 + s] = pk;
            }
        }
    }
}

// ---------------- flash attention ----------------
// Grid 512 (2 exact rounds), XCD swizzle. 256 q/block, 64 q/wave: each
// K/V ds_read_b128 feeds 2 MFMAs. kv tiles 64, dbuf.
#define EXPC 0.18033688011112042f   // 0.125 * log2(e)
#define LOG2E 1.4426950408889634f

__device__ inline uint2v half_swap(unsigned c, unsigned d, int hi) {
#if __has_builtin(__builtin_amdgcn_permlane32_swap)
    return __builtin_amdgcn_permlane32_swap(c, d, false, false);
#else
    unsigned send = hi ? c : d;
    unsigned recv = (unsigned)__shfl_xor((int)send, 32, 64);
    uint2v r;
    r.x = hi ? recv : c;     // frag low dword
    r.y = hi ? d : recv;     // frag high dword
    return r;
#endif
}

__device__ inline float fast_exp2(float x) {
#if __has_builtin(__builtin_amdgcn_exp2f)
    return __builtin_amdgcn_exp2f(x);
#else
    float r;
    asm("v_exp_f32 %0, %1" : "=v"(r) : "v"(x));
    return r;
#endif
}

__device__ inline unsigned cvt_pk_bf16(float a, float b) {
    unsigned r;
    asm("v_cvt_pk_bf16_f32 %0, %1, %2" : "=v"(r) : "v"(a), "v"(b));
    return r;
}

__global__ __launch_bounds__(256, 2) void attn(
    const short* __restrict__ q, const short* __restrict__ k,
    const short* __restrict__ vt, const float* __restrict__ mask,
    float* __restrict__ out)
{
    __shared__ __align__(16) short Ks[2][64 * 64];
    __shared__ __align__(16) short Vs[2][64 * 64];
    __shared__ __align__(16) float Ems[1024];      // fp32 mask * log2(e)

    const int t = threadIdx.x;
    const int lane = t & 63;
    const int wq = t >> 6;
    const int lane31 = lane & 31;
    const int hi = lane >> 5;

    const int id = blockIdx.x;                 // 0..511
    const int bh = (id >> 5) * 8 + (id & 7);   // 0..127
    const int qt = (id >> 3) & 3;              // 0..3 (256-row q tile)
    const int b = bh >> 4, h = bh & 15;

    const short* qbase = q + (size_t)(bh * 1024 + qt * 256) * 64;
    const short* kbase = k + (size_t)bh * 1024 * 64;
    const short* vbase = vt + (size_t)bh * 64 * 1024;

    // stage mask once (pre-scaled by log2 e), fp32
    {
        float4 mv = ((const float4*)(mask + b * 1024))[t];
        float4 o4;
        o4.x = mv.x * LOG2E; o4.y = mv.y * LOG2E;
        o4.z = mv.z * LOG2E; o4.w = mv.w * LOG2E;
        *(float4*)&Ems[t * 4] = o4;
    }

    // Q fragments: 64 q rows/wave (2 halves of 32). B-operand n=q, k=d.
    short8 qf[2][4];
    #pragma unroll
    for (int qh = 0; qh < 2; ++qh)
        #pragma unroll
        for (int kc = 0; kc < 4; ++kc)
            qf[qh][kc] = *(const short8*)&qbase[
                (size_t)(wq * 64 + qh * 32 + lane31) * 64 + kc * 16 + hi * 8];

    // prefetch KV tile 0
    #pragma unroll
    for (int i = 0; i < 2; ++i) {
        int c = i * 256 + t;
        int row = c >> 3;
        int gc = (c & 7) ^ (row & 7);
        __builtin_amdgcn_global_load_lds(AS1(kbase + (size_t)row * 64 + gc * 8),
                                         AS3(&Ks[0][c * 8]), 16, 0, 0);
        __builtin_amdgcn_global_load_lds(AS1(vbase + (size_t)row * 1024 + gc * 8),
                                         AS3(&Vs[0][c * 8]), 16, 0, 0);
    }

    f32x16 o_acc[2][2] = {};
    f32x2 lacc[2] = {{0.f, 0.f}, {0.f, 0.f}};

    for (int kt = 0; kt < 16; ++kt) {
        __syncthreads();
        if (kt < 15) {
            int kv1 = (kt + 1) * 64;
            int nb = (kt + 1) & 1;
            #pragma unroll
            for (int i = 0; i < 2; ++i) {
                int c = i * 256 + t;
                int row = c >> 3;
                int gc = (c & 7) ^ (row & 7);
                __builtin_amdgcn_global_load_lds(
                    AS1(kbase + (size_t)(kv1 + row) * 64 + gc * 8),
                    AS3(&Ks[nb][c * 8]), 16, 0, 0);
                __builtin_amdgcn_global_load_lds(
                    AS1(vbase + (size_t)row * 1024 + kv1 + gc * 8),
                    AS3(&Vs[nb][c * 8]), 16, 0, 0);
            }
        }
        const short* ks_ = Ks[kt & 1];
        const short* vs_ = Vs[kt & 1];
        const int kv0 = kt * 64;

        // S^T[kv][q]: A = K (m=kv), B = Q (n=q). 16 MFMA from 8 K-reads.
        f32x16 sacc[2][2] = {};
        #pragma unroll
        for (int kc = 0; kc < 4; ++kc) {
            short8 ak[2];
            #pragma unroll
            for (int mt = 0; mt < 2; ++mt) {
                int rr = mt * 32 + lane31;
                ak[mt] = *(short8*)&ks_[rr * 64 + ((kc * 2 + hi) ^ (rr & 7)) * 8];
            }
            #pragma unroll
            for (int qh = 0; qh < 2; ++qh)
                #pragma unroll
                for (int mt = 0; mt < 2; ++mt)
                    sacc[qh][mt] = __builtin_amdgcn_mfma_f32_32x32x16_bf16(
                        ak[mt], qf[qh][kc], sacc[qh][mt], 0, 0, 0);
        }

        // softmax numerators; mask read shared across both q-halves.
        unsigned pk[2][2][4][2];
        #pragma unroll
        for (int mt = 0; mt < 2; ++mt) {
            #pragma unroll
            for (int rg = 0; rg < 4; ++rg) {
                int kvl = mt * 32 + rg * 8 + hi * 4;
                f32x4 mk = *(const f32x4*)&Ems[kv0 + kvl];
                #pragma unroll
                for (int qh = 0; qh < 2; ++qh) {
                    f32x4 sv;
                    sv.x = sacc[qh][mt][rg * 4 + 0];
                    sv.y = sacc[qh][mt][rg * 4 + 1];
                    sv.z = sacc[qh][mt][rg * 4 + 2];
                    sv.w = sacc[qh][mt][rg * 4 + 3];
                    f32x4 ev = sv * EXPC + mk;
                    float p0 = fast_exp2(ev.x);
                    float p1 = fast_exp2(ev.y);
                    float p2 = fast_exp2(ev.z);
                    float p3 = fast_exp2(ev.w);
                    f32x2 pa; pa.x = p0; pa.y = p2;
                    f32x2 pb; pb.x = p1; pb.y = p3;
                    lacc[qh] += pa + pb;
                    pk[qh][mt][rg][0] = cvt_pk_bf16(p0, p1);
                    pk[qh][mt][rg][1] = cvt_pk_bf16(p2, p3);
                }
            }
        }

        // O[q][d] += P·Vt: 16 MFMA from 8 V-reads (shared across q-halves).
        #pragma unroll
        for (int kc = 0; kc < 4; ++kc) {
            const int mt = kc >> 1, glo = (kc & 1) * 2;
            short8 bv_[2];
            #pragma unroll
            for (int nt = 0; nt < 2; ++nt) {
                int rv = nt * 32 + lane31;
                bv_[nt] = *(short8*)&vs_[rv * 64 + ((kc * 2 + hi) ^ (rv & 7)) * 8];
            }
            #pragma unroll
            for (int qh = 0; qh < 2; ++qh) {
                uint2v s0 = half_swap(pk[qh][mt][glo][0], pk[qh][mt][glo + 1][0], hi);
                uint2v s1 = half_swap(pk[qh][mt][glo][1], pk[qh][mt][glo + 1][1], hi);
                int4v fr; fr.x = (int)s0.x; fr.y = (int)s1.x; fr.z = (int)s0.y; fr.w = (int)s1.y;
                short8 ap = *(short8*)&fr;
                #pragma unroll
                for (int nt = 0; nt < 2; ++nt)
                    o_acc[qh][nt] = __builtin_amdgcn_mfma_f32_32x32x16_bf16(
                        ap, bv_[nt], o_acc[qh][nt], 0, 0, 0);
            }
        }
    }

    // finalize l per q-half; halves hold disjoint kv partials
    float invl[2];
    #pragma unroll
    for (int qh = 0; qh < 2; ++qh) {
        float l_sum = lacc[qh].x + lacc[qh].y;
        l_sum += __shfl_xor(l_sum, 32, 64);
        invl[qh] = 1.f / l_sum;
    }

    // epilogue: row (within qh) = rg*8 + hi*4 + r, col d = nt*32 + lane31
    #pragma unroll
    for (int qh = 0; qh < 2; ++qh) {
        #pragma unroll
        for (int rg = 0; rg < 4; ++rg) {
            #pragma unroll
            for (int r = 0; r < 4; ++r) {
                int qrow_l = rg * 8 + hi * 4 + r;
                float lv = __shfl(invl[qh], qrow_l, 64);
                int qrow = qt * 256 + wq * 64 + qh * 32 + qrow_l;
                size_t base = (size_t)(b * 1024 + qrow) * 1024 + h * 64;
                #pragma unroll
                for (int nt = 0; nt < 2; ++nt)
                    out[base + nt * 32 + lane31] = o_acc[qh][nt][rg * 4 + r] * lv;
            }
        }
    }
}

extern "C" void kernel_launch(void* const* d_in, const int* in_sizes, int n_in,
                              void* d_out, int out_size, void* d_ws, size_t ws_size,
                              hipStream_t stream) {
    const float* hs   = (const float*)d_in[0];
    const float* kvs  = (const float*)d_in[1];
    const float* mask = (const float*)d_in[2];
    const float* Wq   = (const float*)d_in[3];
    const float* bq   = (const float*)d_in[4];
    const float* Wk   = (const float*)d_in[5];
    const float* bk   = (const float*)d_in[6];
    const float* Wv   = (const float*)d_in[7];
    const float* bv   = (const float*)d_in[8];
    float* outp = (float*)d_out;

    const size_t big = (size_t)8 * 1024 * 1024;
    const size_t wsz = (size_t)1024 * 1024;
    short* q_ws  = (short*)d_ws;
    short* k_ws  = q_ws  + big;
    short* vt_ws = k_ws  + big;
    short* hsb   = vt_ws + big;
    short* kvb   = hsb   + big;
    short* wqb   = kvb   + big;
    short* wkb   = wqb   + wsz;
    short* wvb   = wkb   + wsz;

    cvt_bf16<<<dim3(1024, 5), 256, 0, stream>>>(hs, kvs, Wq, Wk, Wv,
                                                hsb, kvb, wqb, wkb, wvb);
    q_gemm<<<dim3(64, 8), 256, 0, stream>>>(hsb, wqb, bq, q_ws);
    kv_gemm<<<dim3(64, 8), 256, 0, stream>>>(kvb, wkb, wvb, bk, bv, k_ws, vt_ws);
    attn<<<dim3(512), 256, 0, stream>>>(q_ws, k_ws, vt_ws, mask, outp);
}